// Round 13
// baseline (414.848 us; speedup 1.0000x reference)
//
#include <hip/hip_runtime.h>
#include <hip/hip_bf16.h>
#include <math.h>

#define N_NODES 25000
#define N_TOT   50000     // pos nodes [0,N) + neg-dst virtual nodes [N,2N)
#define N_EDGES 250000
#define NH 4
#define F 256   // H*D
#define NEG_SLOPE 0.2f

typedef float  f32x4 __attribute__((ext_vector_type(4)));
typedef short  s16x8 __attribute__((ext_vector_type(8)));
typedef ushort u16x8 __attribute__((ext_vector_type(8)));

__device__ inline ushort f2bf(float f) {
    uint u = __float_as_uint(f);
    u += 0x7FFF + ((u >> 16) & 1);   // round-to-nearest-even
    return (ushort)(u >> 16);
}
__device__ inline float bf2f(ushort s) { return __uint_as_float(((uint)s) << 16); }

// ---------- x -> bf16 cast ----------
__global__ __launch_bounds__(256) void k_cast(const float* __restrict__ x,
                                              ushort* __restrict__ xb) {
    int i = blockIdx.x * blockDim.x + threadIdx.x;
    if (i * 4 >= N_NODES * F) return;
    float4 v = *(const float4*)&x[i * 4];
    ushort4 o;
    o.x = f2bf(v.x); o.y = f2bf(v.y); o.z = f2bf(v.z); o.w = f2bf(v.w);
    *(ushort4*)&xb[i * 4] = o;
}

// ---------- combined CSR build (pos dst + neg dst as virtual nodes) ----------
__global__ void k_degree(const int* __restrict__ dst, const int* __restrict__ ndst,
                         int* deg) {
    int e = blockIdx.x * blockDim.x + threadIdx.x;
    if (e >= N_EDGES) return;
    atomicAdd(&deg[dst[e]], 1);
    atomicAdd(&deg[N_NODES + ndst[e]], 1);
}

__global__ __launch_bounds__(1024) void k_scan(const int* __restrict__ deg, int* rowptr) {
    __shared__ int sums[1024];
    const int CH = 49;  // 1024*49 = 50176 >= 50000
    int t = threadIdx.x;
    int base = t * CH;
    int s = 0;
    for (int i = 0; i < CH; ++i) {
        int idx = base + i;
        if (idx < N_TOT) s += deg[idx];
    }
    sums[t] = s;
    __syncthreads();
    for (int off = 1; off < 1024; off <<= 1) {
        int v = (t >= off) ? sums[t - off] : 0;
        __syncthreads();
        sums[t] += v;
        __syncthreads();
    }
    int prefix = (t == 0) ? 0 : sums[t - 1];
    for (int i = 0; i < CH; ++i) {
        int idx = base + i;
        if (idx < N_TOT) {
            rowptr[idx] = prefix;
            prefix += deg[idx];
        }
    }
    if (t == 1023) rowptr[N_TOT] = prefix;   // == 2E
}

__global__ void k_bucket(const int* __restrict__ src, const int* __restrict__ dst,
                         const int* __restrict__ nsrc, const int* __restrict__ ndst,
                         const int* __restrict__ rowptr, int* cursor,
                         int* cesrc, int* cedst, int* ceid) {
    int e = blockIdx.x * blockDim.x + threadIdx.x;
    if (e >= N_EDGES) return;
    {   // positive edge -> slot in [0, E)
        int d = dst[e];
        int p = atomicAdd(&cursor[d], 1);
        int slot = rowptr[d] + p;
        cesrc[slot] = src[e];
        cedst[slot] = d;
        ceid[slot]  = e;
    }
    {   // negative edge -> slot in [E, 2E)
        int d = N_NODES + ndst[e];
        int p = atomicAdd(&cursor[d], 1);
        int slot = rowptr[d] + p;
        cesrc[slot] = nsrc[e];
        cedst[slot] = ndst[e];
        ceid[slot]  = N_EDGES + e;
    }
}

// ---------- W prep: transpose to bf16 [n][k] ----------
__global__ __launch_bounds__(256) void k_wprep(const float* __restrict__ W,
        short* __restrict__ Hi) {
    __shared__ float T[64][65];
    int bk = (blockIdx.x & 3) * 64;
    int bn = (blockIdx.x >> 2) * 64;
    int t = threadIdx.x;
    int r = t >> 6, c = t & 63;
    #pragma unroll
    for (int i = 0; i < 64; i += 4)
        T[r + i][c] = W[(bk + r + i) * 256 + bn + c];
    __syncthreads();
    #pragma unroll
    for (int i = 0; i < 64; i += 4) {
        float w = T[c][r + i];
        Hi[(bn + r + i) * 256 + bk + c] = (short)f2bf(w);
    }
}

// ---------- bf16 MFMA GEMM, 32-row tiles (782 blocks -> ~3 blocks/CU) ----------
__global__ __launch_bounds__(256) void k_gemm(const ushort* __restrict__ A,
        const short* __restrict__ Wt,
        const float* __restrict__ alv, const float* __restrict__ arv,
        ushort* __restrict__ Cbf, float* __restrict__ el, float* __restrict__ er,
        int M) {
    __shared__ short As[2][32][32];
    __shared__ short Ws[2][256][32];
    int tid = threadIdx.x;
    int w = tid >> 6, l = tid & 63;
    int row0 = blockIdx.x * 32;

    f32x4 acc[2][4];
    #pragma unroll
    for (int i = 0; i < 2; ++i)
        #pragma unroll
        for (int j = 0; j < 4; ++j)
            acc[i][j] = (f32x4){0.f, 0.f, 0.f, 0.f};

    const int sr = tid >> 2;              // A staging row (tid<128 -> 0..31)
    const int sk = tid & 3;               // 16B k-slot 0..3
    const int sa = sk ^ ((sr >> 1) & 3);  // swizzled slot

    s16x8 aReg;
    s16x8 whr[4];

    // prologue: chunk 0 -> regs -> buf 0
    {
        aReg = (s16x8){0,0,0,0,0,0,0,0};
        if (tid < 128) {
            int gr = row0 + sr;
            if (gr < M) aReg = *(const s16x8*)&A[gr * 256 + sk * 8];
        }
        #pragma unroll
        for (int r = 0; r < 4; ++r) {
            int n = (tid >> 2) + 64 * r;
            whr[r] = *(const s16x8*)&Wt[n * 256 + sk * 8];
        }
        if (tid < 128) *(s16x8*)&As[0][sr][sa * 8] = aReg;
        #pragma unroll
        for (int r = 0; r < 4; ++r) {
            int n = (tid >> 2) + 64 * r;
            int sw = sk ^ ((n >> 1) & 3);
            *(s16x8*)&Ws[0][n][sw * 8] = whr[r];
        }
    }
    __syncthreads();

    const int r16 = l & 15, kg = l >> 4;
    for (int c = 0; c < 8; ++c) {
        const int b = c & 1;
        if (c < 7) {
            int kc = (c + 1) * 32;
            aReg = (s16x8){0,0,0,0,0,0,0,0};
            if (tid < 128) {
                int gr = row0 + sr;
                if (gr < M) aReg = *(const s16x8*)&A[gr * 256 + kc + sk * 8];
            }
            #pragma unroll
            for (int r = 0; r < 4; ++r) {
                int n = (tid >> 2) + 64 * r;
                whr[r] = *(const s16x8*)&Wt[n * 256 + kc + sk * 8];
            }
        }
        s16x8 ah[2], bh[4];
        #pragma unroll
        for (int i = 0; i < 2; ++i) {
            int r = i * 16 + r16;
            int s = (kg ^ ((r >> 1) & 3)) * 8;
            ah[i] = *(const s16x8*)&As[b][r][s];
        }
        #pragma unroll
        for (int j = 0; j < 4; ++j) {
            int cc = w * 64 + j * 16 + r16;
            int s = (kg ^ ((cc >> 1) & 3)) * 8;
            bh[j] = *(const s16x8*)&Ws[b][cc][s];
        }
        #pragma unroll
        for (int i = 0; i < 2; ++i)
            #pragma unroll
            for (int j = 0; j < 4; ++j)
                acc[i][j] = __builtin_amdgcn_mfma_f32_16x16x32_bf16(ah[i], bh[j], acc[i][j], 0, 0, 0);
        if (c < 7) {
            if (tid < 128) *(s16x8*)&As[b ^ 1][sr][sa * 8] = aReg;
            #pragma unroll
            for (int r = 0; r < 4; ++r) {
                int n = (tid >> 2) + 64 * r;
                int sw = sk ^ ((n >> 1) & 3);
                *(s16x8*)&Ws[b ^ 1][n][sw * 8] = whr[r];
            }
        }
        __syncthreads();
    }

    // ---- epilogue: fused el/er + bf16 feat write ----
    float ac4[4], rc4[4];
    #pragma unroll
    for (int j = 0; j < 4; ++j) {
        ac4[j] = alv[w * 64 + j * 16 + r16];
        rc4[j] = arv[w * 64 + j * 16 + r16];
    }
    #pragma unroll
    for (int i = 0; i < 2; ++i) {
        #pragma unroll
        for (int q = 0; q < 4; ++q) {
            int gr = row0 + i * 16 + kg * 4 + q;
            float pel = 0.f, per = 0.f;
            #pragma unroll
            for (int j = 0; j < 4; ++j) {
                float v = acc[i][j][q];
                pel += v * ac4[j];
                per += v * rc4[j];
            }
            pel += __shfl_xor(pel, 1);  per += __shfl_xor(per, 1);
            pel += __shfl_xor(pel, 2);  per += __shfl_xor(per, 2);
            pel += __shfl_xor(pel, 4);  per += __shfl_xor(per, 4);
            pel += __shfl_xor(pel, 8);  per += __shfl_xor(per, 8);
            if (r16 == 0 && gr < M) {
                el[gr * NH + w] = pel;
                er[gr * NH + w] = per;
            }
        }
    }
    #pragma unroll
    for (int i = 0; i < 2; ++i)
        #pragma unroll
        for (int j = 0; j < 4; ++j) {
            int cc = w * 64 + j * 16 + r16;
            #pragma unroll
            for (int q = 0; q < 4; ++q) {
                int gr = row0 + i * 16 + kg * 4 + q;
                if (gr < M) Cbf[gr * 256 + cc] = f2bf(acc[i][j][q]);
            }
        }
}

// ---------- fused attention + aggregation: 1 wave/node, half-wave = 1 edge ----------
// 32 lanes x uint4 (16B) cover a full 512B feat row; half-waves process the
// even/odd edges of the node; unroll-2 keeps 2x16B in flight per lane.
__global__ __launch_bounds__(256) void k_node(const ushort* __restrict__ featbf,
        const float* __restrict__ el, const float* __restrict__ er,
        const int* __restrict__ rowptr, const int* __restrict__ cesrc,
        const float* __restrict__ bias,
        ushort* __restrict__ hbf) {
    int t = threadIdx.x;
    int n = blockIdx.x * 4 + (t >> 6);
    if (n >= N_NODES) return;
    int l = t & 63;
    int half = l >> 5;         // which edge of the pair
    int lc = l & 31;
    int c0 = lc * 8;           // 8 columns per lane
    int h = lc >> 3;           // head (8 lanes per head)
    float ern = er[n * NH + h];
    int r0 = rowptr[n], r1 = rowptr[n + 1];
    float S = 0.f;
    float ac[8] = {0.f, 0.f, 0.f, 0.f, 0.f, 0.f, 0.f, 0.f};
    int p = r0 + half;
    for (; p + 2 < r1; p += 4) {
        int s0 = cesrc[p], s1 = cesrc[p + 2];
        uint4 q0 = *(const uint4*)&featbf[s0 * F + c0];
        uint4 q1 = *(const uint4*)&featbf[s1 * F + c0];
        float e0 = el[s0 * NH + h] + ern;
        float e1 = el[s1 * NH + h] + ern;
        e0 = e0 > 0.f ? e0 : NEG_SLOPE * e0;
        e1 = e1 > 0.f ? e1 : NEG_SLOPE * e1;
        float a0 = __expf(e0), a1 = __expf(e1);
        S += a0 + a1;
        ac[0] += a0 * bf2f((ushort)(q0.x & 0xFFFF)) + a1 * bf2f((ushort)(q1.x & 0xFFFF));
        ac[1] += a0 * bf2f((ushort)(q0.x >> 16))    + a1 * bf2f((ushort)(q1.x >> 16));
        ac[2] += a0 * bf2f((ushort)(q0.y & 0xFFFF)) + a1 * bf2f((ushort)(q1.y & 0xFFFF));
        ac[3] += a0 * bf2f((ushort)(q0.y >> 16))    + a1 * bf2f((ushort)(q1.y >> 16));
        ac[4] += a0 * bf2f((ushort)(q0.z & 0xFFFF)) + a1 * bf2f((ushort)(q1.z & 0xFFFF));
        ac[5] += a0 * bf2f((ushort)(q0.z >> 16))    + a1 * bf2f((ushort)(q1.z >> 16));
        ac[6] += a0 * bf2f((ushort)(q0.w & 0xFFFF)) + a1 * bf2f((ushort)(q1.w & 0xFFFF));
        ac[7] += a0 * bf2f((ushort)(q0.w >> 16))    + a1 * bf2f((ushort)(q1.w >> 16));
    }
    if (p < r1) {
        int s0 = cesrc[p];
        uint4 q0 = *(const uint4*)&featbf[s0 * F + c0];
        float e0 = el[s0 * NH + h] + ern;
        e0 = e0 > 0.f ? e0 : NEG_SLOPE * e0;
        float a0 = __expf(e0);
        S += a0;
        ac[0] += a0 * bf2f((ushort)(q0.x & 0xFFFF));
        ac[1] += a0 * bf2f((ushort)(q0.x >> 16));
        ac[2] += a0 * bf2f((ushort)(q0.y & 0xFFFF));
        ac[3] += a0 * bf2f((ushort)(q0.y >> 16));
        ac[4] += a0 * bf2f((ushort)(q0.z & 0xFFFF));
        ac[5] += a0 * bf2f((ushort)(q0.z >> 16));
        ac[6] += a0 * bf2f((ushort)(q0.w & 0xFFFF));
        ac[7] += a0 * bf2f((ushort)(q0.w >> 16));
    }
    // cross-half reduction
    S += __shfl_xor(S, 32);
    #pragma unroll
    for (int j = 0; j < 8; ++j) ac[j] += __shfl_xor(ac[j], 32);
    if (half == 0) {
        float inv = S > 0.f ? 1.f / S : 0.f;
        float4 b0 = *(const float4*)&bias[c0];
        float4 b1 = *(const float4*)&bias[c0 + 4];
        float o0 = ac[0] * inv + b0.x;  float o1 = ac[1] * inv + b0.y;
        float o2 = ac[2] * inv + b0.z;  float o3 = ac[3] * inv + b0.w;
        float o4 = ac[4] * inv + b1.x;  float o5 = ac[5] * inv + b1.y;
        float o6 = ac[6] * inv + b1.z;  float o7 = ac[7] * inv + b1.w;
        o0 = o0 > 0.f ? o0 : 0.f;  o1 = o1 > 0.f ? o1 : 0.f;
        o2 = o2 > 0.f ? o2 : 0.f;  o3 = o3 > 0.f ? o3 : 0.f;
        o4 = o4 > 0.f ? o4 : 0.f;  o5 = o5 > 0.f ? o5 : 0.f;
        o6 = o6 > 0.f ? o6 : 0.f;  o7 = o7 > 0.f ? o7 : 0.f;
        uint4 pk;
        pk.x = (uint)f2bf(o0) | ((uint)f2bf(o1) << 16);
        pk.y = (uint)f2bf(o2) | ((uint)f2bf(o3) << 16);
        pk.z = (uint)f2bf(o4) | ((uint)f2bf(o5) << 16);
        pk.w = (uint)f2bf(o6) | ((uint)f2bf(o7) << 16);
        *(uint4*)&hbf[n * F + c0] = pk;
    }
}

// ---------- final dot scores: 16 lanes/edge; ALL edges dst-sorted, eid scatter ----------
__global__ __launch_bounds__(256) void k_score(const ushort* __restrict__ h,
        const int* __restrict__ cesrc, const int* __restrict__ cedst,
        const int* __restrict__ ceid,
        float* __restrict__ out) {
    int g = blockIdx.x * 16 + (threadIdx.x >> 4);   // slot 0..2E-1
    int sub = threadIdx.x & 15;                     // 16B segment within row
    int u = cesrc[g];
    int v = cedst[g];
    float* o = out + (size_t)ceid[g] * NH;
    u16x8 a0 = *(const u16x8*)&h[u * F + sub * 16];
    u16x8 a1 = *(const u16x8*)&h[u * F + sub * 16 + 8];
    u16x8 b0 = *(const u16x8*)&h[v * F + sub * 16];
    u16x8 b1 = *(const u16x8*)&h[v * F + sub * 16 + 8];
    float p = 0.f;
    #pragma unroll
    for (int i = 0; i < 8; ++i) {
        p += bf2f(a0[i]) * bf2f(b0[i]);
        p += bf2f(a1[i]) * bf2f(b1[i]);
    }
    p += __shfl_xor(p, 1);
    p += __shfl_xor(p, 2);
    if ((sub & 3) == 0) o[sub >> 2] = p;   // head = sub>>2
}

extern "C" void kernel_launch(void* const* d_in, const int* in_sizes, int n_in,
                              void* d_out, int out_size, void* d_ws, size_t ws_size,
                              hipStream_t stream) {
    const float* x    = (const float*)d_in[0];
    const int* src    = (const int*)d_in[1];
    const int* dst    = (const int*)d_in[2];
    const int* nsrc   = (const int*)d_in[3];
    const int* ndst   = (const int*)d_in[4];
    const float* W[3]  = {(const float*)d_in[5], (const float*)d_in[9],  (const float*)d_in[13]};
    const float* al[3] = {(const float*)d_in[6], (const float*)d_in[10], (const float*)d_in[14]};
    const float* ar[3] = {(const float*)d_in[7], (const float*)d_in[11], (const float*)d_in[15]};
    const float* bs[3] = {(const float*)d_in[8], (const float*)d_in[12], (const float*)d_in[16]};

    char* p = (char*)d_ws;
    auto alloc = [&](size_t bytes) {
        char* r = p;
        p += (bytes + 255) & ~size_t(255);
        return r;
    };
    ushort* xbf    = (ushort*)alloc(sizeof(ushort) * N_NODES * F);
    ushort* featbf = (ushort*)alloc(sizeof(ushort) * N_NODES * F);
    ushort* hA     = (ushort*)alloc(sizeof(ushort) * N_NODES * F);
    ushort* hB     = (ushort*)alloc(sizeof(ushort) * N_NODES * F);
    float* el    = (float*)alloc(sizeof(float) * N_NODES * NH);
    float* er    = (float*)alloc(sizeof(float) * N_NODES * NH);
    int* deg     = (int*)alloc(sizeof(int) * N_TOT);
    int* cursor  = (int*)alloc(sizeof(int) * N_TOT);
    int* rowptr  = (int*)alloc(sizeof(int) * (N_TOT + 1));
    int* cesrc   = (int*)alloc(sizeof(int) * 2 * N_EDGES);
    int* cedst   = (int*)alloc(sizeof(int) * 2 * N_EDGES);
    int* ceid    = (int*)alloc(sizeof(int) * 2 * N_EDGES);
    short* wt[3];
    for (int i = 0; i < 3; ++i)
        wt[i] = (short*)alloc(sizeof(short) * 256 * 256);

    (void)hipMemsetAsync(deg, 0, sizeof(int) * N_TOT, stream);
    (void)hipMemsetAsync(cursor, 0, sizeof(int) * N_TOT, stream);

    int eb = (N_EDGES + 255) / 256;
    k_cast<<<(N_NODES * F / 4 + 255) / 256, 256, 0, stream>>>(x, xbf);
    k_degree<<<eb, 256, 0, stream>>>(dst, ndst, deg);
    k_scan<<<1, 1024, 0, stream>>>(deg, rowptr);
    k_bucket<<<eb, 256, 0, stream>>>(src, dst, nsrc, ndst, rowptr, cursor,
                                     cesrc, cedst, ceid);
    for (int L = 0; L < 3; ++L)
        k_wprep<<<16, 256, 0, stream>>>(W[L], wt[L]);

    const ushort* in_h = xbf;
    ushort* outs[3] = {hA, hB, hA};   // h1 dead by the time h3 is written
    int gemm_grid = (N_NODES + 31) / 32;
    int node_grid = (N_NODES + 3) / 4;
    for (int L = 0; L < 3; ++L) {
        k_gemm<<<gemm_grid, 256, 0, stream>>>(in_h, wt[L], al[L], ar[L],
                                              featbf, el, er, N_NODES);
        k_node<<<node_grid, 256, 0, stream>>>(featbf, el, er, rowptr, cesrc, bs[L], outs[L]);
        in_h = outs[L];
    }
    k_score<<<(2 * N_EDGES) / 16, 256, 0, stream>>>(outs[2], cesrc, cedst, ceid, (float*)d_out);
}

// Round 15
// 325.178 us; speedup vs baseline: 1.2758x; 1.2758x over previous
//
#include <hip/hip_runtime.h>
#include <hip/hip_bf16.h>
#include <math.h>

#define N_NODES 25000
#define N_TOT   50000     // pos nodes [0,N) + neg-dst virtual nodes [N,2N)
#define N_EDGES 250000
#define NH 4
#define F 256   // H*D
#define NEG_SLOPE 0.2f
#define SCAN_BLKS ((N_TOT + 255) / 256)   // 196

typedef float  f32x4 __attribute__((ext_vector_type(4)));
typedef short  s16x8 __attribute__((ext_vector_type(8)));
typedef ushort u16x8 __attribute__((ext_vector_type(8)));

__device__ inline ushort f2bf(float f) {
    uint u = __float_as_uint(f);
    u += 0x7FFF + ((u >> 16) & 1);   // round-to-nearest-even
    return (ushort)(u >> 16);
}
__device__ inline float bf2f(ushort s) { return __uint_as_float(((uint)s) << 16); }

// ---------- x -> bf16 cast ----------
__global__ __launch_bounds__(256) void k_cast(const float* __restrict__ x,
                                              ushort* __restrict__ xb) {
    int i = blockIdx.x * blockDim.x + threadIdx.x;
    if (i * 4 >= N_NODES * F) return;
    float4 v = *(const float4*)&x[i * 4];
    ushort4 o;
    o.x = f2bf(v.x); o.y = f2bf(v.y); o.z = f2bf(v.z); o.w = f2bf(v.w);
    *(ushort4*)&xb[i * 4] = o;
}

// ---------- combined CSR build (pos dst + neg dst as virtual nodes) ----------
__global__ void k_degree(const int* __restrict__ dst, const int* __restrict__ ndst,
                         int* deg) {
    int e = blockIdx.x * blockDim.x + threadIdx.x;
    if (e >= N_EDGES) return;
    atomicAdd(&deg[dst[e]], 1);
    atomicAdd(&deg[N_NODES + ndst[e]], 1);
}

// ---- hierarchical exclusive scan over deg[N_TOT] -> rowptr ----
__global__ __launch_bounds__(256) void k_scan_blk(const int* __restrict__ deg,
        int* __restrict__ rowptr, int* __restrict__ bsum) {
    __shared__ int sh[256];
    int t = threadIdx.x;
    int i = blockIdx.x * 256 + t;
    int v = (i < N_TOT) ? deg[i] : 0;
    sh[t] = v;
    __syncthreads();
    #pragma unroll
    for (int off = 1; off < 256; off <<= 1) {
        int u = (t >= off) ? sh[t - off] : 0;
        __syncthreads();
        sh[t] += u;
        __syncthreads();
    }
    if (i < N_TOT) rowptr[i] = sh[t] - v;    // block-local exclusive prefix
    if (t == 255) bsum[blockIdx.x] = sh[255];
}

__global__ __launch_bounds__(256) void k_scan_top(int* __restrict__ bsum) {
    __shared__ int sh[256];
    int t = threadIdx.x;
    int v = (t < SCAN_BLKS) ? bsum[t] : 0;
    sh[t] = v;
    __syncthreads();
    #pragma unroll
    for (int off = 1; off < 256; off <<= 1) {
        int u = (t >= off) ? sh[t - off] : 0;
        __syncthreads();
        sh[t] += u;
        __syncthreads();
    }
    if (t < SCAN_BLKS) bsum[t] = sh[t] - v;  // exclusive block offsets
}

__global__ __launch_bounds__(256) void k_scan_add(const int* __restrict__ deg,
        int* __restrict__ rowptr, const int* __restrict__ bsum) {
    int i = blockIdx.x * 256 + threadIdx.x;
    if (i < N_TOT) {
        int r = rowptr[i] + bsum[blockIdx.x];
        rowptr[i] = r;
        if (i == N_TOT - 1) rowptr[N_TOT] = r + deg[i];   // == 2E
    }
}

__global__ void k_bucket(const int* __restrict__ src, const int* __restrict__ dst,
                         const int* __restrict__ nsrc, const int* __restrict__ ndst,
                         const int* __restrict__ rowptr, int* cursor,
                         int* cesrc, int* cedst, int* ceid) {
    int e = blockIdx.x * blockDim.x + threadIdx.x;
    if (e >= N_EDGES) return;
    {   // positive edge -> slot in [0, E)
        int d = dst[e];
        int p = atomicAdd(&cursor[d], 1);
        int slot = rowptr[d] + p;
        cesrc[slot] = src[e];
        cedst[slot] = d;
        ceid[slot]  = e;
    }
    {   // negative edge -> slot in [E, 2E)
        int d = N_NODES + ndst[e];
        int p = atomicAdd(&cursor[d], 1);
        int slot = rowptr[d] + p;
        cesrc[slot] = nsrc[e];
        cedst[slot] = ndst[e];
        ceid[slot]  = N_EDGES + e;
    }
}

// ---------- W prep: transpose to bf16 [n][k] ----------
__global__ __launch_bounds__(256) void k_wprep(const float* __restrict__ W,
        short* __restrict__ Hi) {
    __shared__ float T[64][65];
    int bk = (blockIdx.x & 3) * 64;
    int bn = (blockIdx.x >> 2) * 64;
    int t = threadIdx.x;
    int r = t >> 6, c = t & 63;
    #pragma unroll
    for (int i = 0; i < 64; i += 4)
        T[r + i][c] = W[(bk + r + i) * 256 + bn + c];
    __syncthreads();
    #pragma unroll
    for (int i = 0; i < 64; i += 4) {
        float w = T[c][r + i];
        Hi[(bn + r + i) * 256 + bk + c] = (short)f2bf(w);
    }
}

// ---------- bf16 MFMA GEMM (64-row tile, R12-proven) + fused el/er ----------
__global__ __launch_bounds__(256) void k_gemm(const ushort* __restrict__ A,
        const short* __restrict__ Wt,
        const float* __restrict__ alv, const float* __restrict__ arv,
        ushort* __restrict__ Cbf, float* __restrict__ el, float* __restrict__ er,
        int M) {
    __shared__ short As[2][64][32];
    __shared__ short Ws[2][256][32];
    int tid = threadIdx.x;
    int w = tid >> 6, l = tid & 63;
    int row0 = blockIdx.x * 64;

    f32x4 acc[4][4];
    #pragma unroll
    for (int i = 0; i < 4; ++i)
        #pragma unroll
        for (int j = 0; j < 4; ++j)
            acc[i][j] = (f32x4){0.f, 0.f, 0.f, 0.f};

    const int sr = tid >> 2;              // staging row 0..63
    const int sk = tid & 3;               // 16B k-slot 0..3
    const int sa = sk ^ ((sr >> 1) & 3);  // swizzled slot

    s16x8 aReg;
    s16x8 whr[4];

    {
        int gr = row0 + sr;
        aReg = (s16x8){0,0,0,0,0,0,0,0};
        if (gr < M) aReg = *(const s16x8*)&A[gr * 256 + sk * 8];
        #pragma unroll
        for (int r = 0; r < 4; ++r) {
            int n = sr + 64 * r;
            whr[r] = *(const s16x8*)&Wt[n * 256 + sk * 8];
        }
        *(s16x8*)&As[0][sr][sa * 8] = aReg;
        #pragma unroll
        for (int r = 0; r < 4; ++r) {
            int n = sr + 64 * r;
            int sw = sk ^ ((n >> 1) & 3);
            *(s16x8*)&Ws[0][n][sw * 8] = whr[r];
        }
    }
    __syncthreads();

    const int r16 = l & 15, kg = l >> 4;
    for (int c = 0; c < 8; ++c) {
        const int b = c & 1;
        if (c < 7) {
            int kc = (c + 1) * 32;
            int gr = row0 + sr;
            aReg = (s16x8){0,0,0,0,0,0,0,0};
            if (gr < M) aReg = *(const s16x8*)&A[gr * 256 + kc + sk * 8];
            #pragma unroll
            for (int r = 0; r < 4; ++r) {
                int n = sr + 64 * r;
                whr[r] = *(const s16x8*)&Wt[n * 256 + kc + sk * 8];
            }
        }
        s16x8 ah[4], bh[4];
        #pragma unroll
        for (int i = 0; i < 4; ++i) {
            int r = i * 16 + r16;
            int s = (kg ^ ((r >> 1) & 3)) * 8;
            ah[i] = *(const s16x8*)&As[b][r][s];
        }
        #pragma unroll
        for (int j = 0; j < 4; ++j) {
            int cc = w * 64 + j * 16 + r16;
            int s = (kg ^ ((cc >> 1) & 3)) * 8;
            bh[j] = *(const s16x8*)&Ws[b][cc][s];
        }
        #pragma unroll
        for (int i = 0; i < 4; ++i)
            #pragma unroll
            for (int j = 0; j < 4; ++j)
                acc[i][j] = __builtin_amdgcn_mfma_f32_16x16x32_bf16(ah[i], bh[j], acc[i][j], 0, 0, 0);
        if (c < 7) {
            *(s16x8*)&As[b ^ 1][sr][sa * 8] = aReg;
            #pragma unroll
            for (int r = 0; r < 4; ++r) {
                int n = sr + 64 * r;
                int sw = sk ^ ((n >> 1) & 3);
                *(s16x8*)&Ws[b ^ 1][n][sw * 8] = whr[r];
            }
        }
        __syncthreads();
    }

    // ---- epilogue: fused el/er + bf16 feat write ----
    float ac4[4], rc4[4];
    #pragma unroll
    for (int j = 0; j < 4; ++j) {
        ac4[j] = alv[w * 64 + j * 16 + r16];
        rc4[j] = arv[w * 64 + j * 16 + r16];
    }
    #pragma unroll
    for (int i = 0; i < 4; ++i) {
        #pragma unroll
        for (int q = 0; q < 4; ++q) {
            int gr = row0 + i * 16 + kg * 4 + q;
            float pel = 0.f, per = 0.f;
            #pragma unroll
            for (int j = 0; j < 4; ++j) {
                float v = acc[i][j][q];
                pel += v * ac4[j];
                per += v * rc4[j];
            }
            pel += __shfl_xor(pel, 1);  per += __shfl_xor(per, 1);
            pel += __shfl_xor(pel, 2);  per += __shfl_xor(per, 2);
            pel += __shfl_xor(pel, 4);  per += __shfl_xor(per, 4);
            pel += __shfl_xor(pel, 8);  per += __shfl_xor(per, 8);
            if (r16 == 0 && gr < M) {
                el[gr * NH + w] = pel;
                er[gr * NH + w] = per;
            }
        }
    }
    #pragma unroll
    for (int i = 0; i < 4; ++i)
        #pragma unroll
        for (int j = 0; j < 4; ++j) {
            int cc = w * 64 + j * 16 + r16;
            #pragma unroll
            for (int q = 0; q < 4; ++q) {
                int gr = row0 + i * 16 + kg * 4 + q;
                if (gr < M) Cbf[gr * 256 + cc] = f2bf(acc[i][j][q]);
            }
        }
}

// ---------- fused attention + aggregation: 1 wave/node, half-wave = 1 edge ----------
__global__ __launch_bounds__(256) void k_node(const ushort* __restrict__ featbf,
        const float* __restrict__ el, const float* __restrict__ er,
        const int* __restrict__ rowptr, const int* __restrict__ cesrc,
        const float* __restrict__ bias,
        ushort* __restrict__ hbf) {
    int t = threadIdx.x;
    int n = blockIdx.x * 4 + (t >> 6);
    if (n >= N_NODES) return;
    int l = t & 63;
    int half = l >> 5;         // which edge of the pair
    int lc = l & 31;
    int c0 = lc * 8;           // 8 columns per lane
    int h = lc >> 3;           // head (8 lanes per head)
    float ern = er[n * NH + h];
    int r0 = rowptr[n], r1 = rowptr[n + 1];
    float S = 0.f;
    float ac[8] = {0.f, 0.f, 0.f, 0.f, 0.f, 0.f, 0.f, 0.f};
    int p = r0 + half;
    for (; p + 2 < r1; p += 4) {
        int s0 = cesrc[p], s1 = cesrc[p + 2];
        uint4 q0 = *(const uint4*)&featbf[s0 * F + c0];
        uint4 q1 = *(const uint4*)&featbf[s1 * F + c0];
        float e0 = el[s0 * NH + h] + ern;
        float e1 = el[s1 * NH + h] + ern;
        e0 = e0 > 0.f ? e0 : NEG_SLOPE * e0;
        e1 = e1 > 0.f ? e1 : NEG_SLOPE * e1;
        float a0 = __expf(e0), a1 = __expf(e1);
        S += a0 + a1;
        ac[0] += a0 * bf2f((ushort)(q0.x & 0xFFFF)) + a1 * bf2f((ushort)(q1.x & 0xFFFF));
        ac[1] += a0 * bf2f((ushort)(q0.x >> 16))    + a1 * bf2f((ushort)(q1.x >> 16));
        ac[2] += a0 * bf2f((ushort)(q0.y & 0xFFFF)) + a1 * bf2f((ushort)(q1.y & 0xFFFF));
        ac[3] += a0 * bf2f((ushort)(q0.y >> 16))    + a1 * bf2f((ushort)(q1.y >> 16));
        ac[4] += a0 * bf2f((ushort)(q0.z & 0xFFFF)) + a1 * bf2f((ushort)(q1.z & 0xFFFF));
        ac[5] += a0 * bf2f((ushort)(q0.z >> 16))    + a1 * bf2f((ushort)(q1.z >> 16));
        ac[6] += a0 * bf2f((ushort)(q0.w & 0xFFFF)) + a1 * bf2f((ushort)(q1.w & 0xFFFF));
        ac[7] += a0 * bf2f((ushort)(q0.w >> 16))    + a1 * bf2f((ushort)(q1.w >> 16));
    }
    if (p < r1) {
        int s0 = cesrc[p];
        uint4 q0 = *(const uint4*)&featbf[s0 * F + c0];
        float e0 = el[s0 * NH + h] + ern;
        e0 = e0 > 0.f ? e0 : NEG_SLOPE * e0;
        float a0 = __expf(e0);
        S += a0;
        ac[0] += a0 * bf2f((ushort)(q0.x & 0xFFFF));
        ac[1] += a0 * bf2f((ushort)(q0.x >> 16));
        ac[2] += a0 * bf2f((ushort)(q0.y & 0xFFFF));
        ac[3] += a0 * bf2f((ushort)(q0.y >> 16));
        ac[4] += a0 * bf2f((ushort)(q0.z & 0xFFFF));
        ac[5] += a0 * bf2f((ushort)(q0.z >> 16));
        ac[6] += a0 * bf2f((ushort)(q0.w & 0xFFFF));
        ac[7] += a0 * bf2f((ushort)(q0.w >> 16));
    }
    // cross-half reduction
    S += __shfl_xor(S, 32);
    #pragma unroll
    for (int j = 0; j < 8; ++j) ac[j] += __shfl_xor(ac[j], 32);
    if (half == 0) {
        float inv = S > 0.f ? 1.f / S : 0.f;
        float4 b0 = *(const float4*)&bias[c0];
        float4 b1 = *(const float4*)&bias[c0 + 4];
        float o0 = ac[0] * inv + b0.x;  float o1 = ac[1] * inv + b0.y;
        float o2 = ac[2] * inv + b0.z;  float o3 = ac[3] * inv + b0.w;
        float o4 = ac[4] * inv + b1.x;  float o5 = ac[5] * inv + b1.y;
        float o6 = ac[6] * inv + b1.z;  float o7 = ac[7] * inv + b1.w;
        o0 = o0 > 0.f ? o0 : 0.f;  o1 = o1 > 0.f ? o1 : 0.f;
        o2 = o2 > 0.f ? o2 : 0.f;  o3 = o3 > 0.f ? o3 : 0.f;
        o4 = o4 > 0.f ? o4 : 0.f;  o5 = o5 > 0.f ? o5 : 0.f;
        o6 = o6 > 0.f ? o6 : 0.f;  o7 = o7 > 0.f ? o7 : 0.f;
        uint4 pk;
        pk.x = (uint)f2bf(o0) | ((uint)f2bf(o1) << 16);
        pk.y = (uint)f2bf(o2) | ((uint)f2bf(o3) << 16);
        pk.z = (uint)f2bf(o4) | ((uint)f2bf(o5) << 16);
        pk.w = (uint)f2bf(o6) | ((uint)f2bf(o7) << 16);
        *(uint4*)&hbf[n * F + c0] = pk;
    }
}

// ---------- final dot scores: 16 lanes/edge; ALL edges dst-sorted, eid scatter ----------
__global__ __launch_bounds__(256) void k_score(const ushort* __restrict__ h,
        const int* __restrict__ cesrc, const int* __restrict__ cedst,
        const int* __restrict__ ceid,
        float* __restrict__ out) {
    int g = blockIdx.x * 16 + (threadIdx.x >> 4);   // slot 0..2E-1
    int sub = threadIdx.x & 15;                     // 16B segment within row
    int u = cesrc[g];
    int v = cedst[g];
    float* o = out + (size_t)ceid[g] * NH;
    u16x8 a0 = *(const u16x8*)&h[u * F + sub * 16];
    u16x8 a1 = *(const u16x8*)&h[u * F + sub * 16 + 8];
    u16x8 b0 = *(const u16x8*)&h[v * F + sub * 16];
    u16x8 b1 = *(const u16x8*)&h[v * F + sub * 16 + 8];
    float p = 0.f;
    #pragma unroll
    for (int i = 0; i < 8; ++i) {
        p += bf2f(a0[i]) * bf2f(b0[i]);
        p += bf2f(a1[i]) * bf2f(b1[i]);
    }
    p += __shfl_xor(p, 1);
    p += __shfl_xor(p, 2);
    if ((sub & 3) == 0) o[sub >> 2] = p;   // head = sub>>2
}

extern "C" void kernel_launch(void* const* d_in, const int* in_sizes, int n_in,
                              void* d_out, int out_size, void* d_ws, size_t ws_size,
                              hipStream_t stream) {
    const float* x    = (const float*)d_in[0];
    const int* src    = (const int*)d_in[1];
    const int* dst    = (const int*)d_in[2];
    const int* nsrc   = (const int*)d_in[3];
    const int* ndst   = (const int*)d_in[4];
    const float* W[3]  = {(const float*)d_in[5], (const float*)d_in[9],  (const float*)d_in[13]};
    const float* al[3] = {(const float*)d_in[6], (const float*)d_in[10], (const float*)d_in[14]};
    const float* ar[3] = {(const float*)d_in[7], (const float*)d_in[11], (const float*)d_in[15]};
    const float* bs[3] = {(const float*)d_in[8], (const float*)d_in[12], (const float*)d_in[16]};

    char* p = (char*)d_ws;
    auto alloc = [&](size_t bytes) {
        char* r = p;
        p += (bytes + 255) & ~size_t(255);
        return r;
    };
    ushort* xbf    = (ushort*)alloc(sizeof(ushort) * N_NODES * F);
    ushort* featbf = (ushort*)alloc(sizeof(ushort) * N_NODES * F);
    ushort* hA     = (ushort*)alloc(sizeof(ushort) * N_NODES * F);
    ushort* hB     = (ushort*)alloc(sizeof(ushort) * N_NODES * F);
    float* el    = (float*)alloc(sizeof(float) * N_NODES * NH);
    float* er    = (float*)alloc(sizeof(float) * N_NODES * NH);
    int* deg     = (int*)alloc(sizeof(int) * N_TOT);
    int* cursor  = (int*)alloc(sizeof(int) * N_TOT);
    int* rowptr  = (int*)alloc(sizeof(int) * (N_TOT + 1));
    int* bsum    = (int*)alloc(sizeof(int) * SCAN_BLKS);
    int* cesrc   = (int*)alloc(sizeof(int) * 2 * N_EDGES);
    int* cedst   = (int*)alloc(sizeof(int) * 2 * N_EDGES);
    int* ceid    = (int*)alloc(sizeof(int) * 2 * N_EDGES);
    short* wt[3];
    for (int i = 0; i < 3; ++i)
        wt[i] = (short*)alloc(sizeof(short) * 256 * 256);

    (void)hipMemsetAsync(deg, 0, sizeof(int) * N_TOT, stream);
    (void)hipMemsetAsync(cursor, 0, sizeof(int) * N_TOT, stream);

    int eb = (N_EDGES + 255) / 256;
    k_cast<<<(N_NODES * F / 4 + 255) / 256, 256, 0, stream>>>(x, xbf);
    k_degree<<<eb, 256, 0, stream>>>(dst, ndst, deg);
    k_scan_blk<<<SCAN_BLKS, 256, 0, stream>>>(deg, rowptr, bsum);
    k_scan_top<<<1, 256, 0, stream>>>(bsum);
    k_scan_add<<<SCAN_BLKS, 256, 0, stream>>>(deg, rowptr, bsum);
    k_bucket<<<eb, 256, 0, stream>>>(src, dst, nsrc, ndst, rowptr, cursor,
                                     cesrc, cedst, ceid);
    for (int L = 0; L < 3; ++L)
        k_wprep<<<16, 256, 0, stream>>>(W[L], wt[L]);

    const ushort* in_h = xbf;
    ushort* outs[3] = {hA, hB, hA};   // h1 dead by the time h3 is written
    int gemm_grid = (N_NODES + 63) / 64;
    int node_grid = (N_NODES + 3) / 4;
    for (int L = 0; L < 3; ++L) {
        k_gemm<<<gemm_grid, 256, 0, stream>>>(in_h, wt[L], al[L], ar[L],
                                              featbf, el, er, N_NODES);
        k_node<<<node_grid, 256, 0, stream>>>(featbf, el, er, rowptr, cesrc, bs[L], outs[L]);
        in_h = outs[L];
    }
    k_score<<<(2 * N_EDGES) / 16, 256, 0, stream>>>(outs[2], cesrc, cedst, ceid, (float*)d_out);
}